// Round 1
// baseline (592.804 us; speedup 1.0000x reference)
//
#include <hip/hip_runtime.h>
#include <hip/hip_bf16.h>
#include <string.h>

// DeformableConv2d: B=4, C=256, O=256, H=W=64, K=3, pad=1, stride=1
// Plan:
//   K1 weight_pack : fp32 weight (O,C,3,3) -> bf16 A-fragment-ordered [o/32][K'/8][o&31][8], K' = kk*256 + c
//   K2 offmask     : fp32 conv -> offsets(18) + sigmoid(mask)(9) per pixel, stored [row][27][64]
//   K3 deform_gemm : producer waves bilinear-sample -> LDS bf16 B-tile; consumer waves 32x32x16 bf16 MFMA
// Workspace: ws_off = 256*27*64 f32 (1769472 B), ws_b = 256*2304 bf16 (1179648 B) => 2949120 B total.

typedef __attribute__((ext_vector_type(8))) short short8;
typedef __attribute__((ext_vector_type(16))) float floatx16;

__device__ __forceinline__ unsigned bfbits(float f) {
    unsigned u;
    __builtin_memcpy(&u, &f, 4);
    return (u + 0x7fffu + ((u >> 16) & 1u)) >> 16;   // RNE f32->bf16
}
__device__ __forceinline__ unsigned pack_bf16(float lo, float hi) {
    return bfbits(lo) | (bfbits(hi) << 16);
}

// ---------------------------------------------------------------------------
// K1: weight pack.  u indexes (nt, ku, no): out[u*8 + j] = bf16(weight[o][c0+j][kk])
// with o = nt*32+no, kk = ku>>5, c0 = (ku&31)*8.  73728 threads total.
// ---------------------------------------------------------------------------
__global__ __launch_bounds__(256) void weight_pack_kernel(
    const float* __restrict__ w, unsigned short* __restrict__ ws_b)
{
    int u = blockIdx.x * 256 + threadIdx.x;      // 0..73727
    int no = u & 31;
    int t2 = u >> 5;
    int ku = t2 % 288;
    int nt = t2 / 288;
    int o  = nt * 32 + no;
    int kk = ku >> 5;
    int c0 = (ku & 31) * 8;
    unsigned pk[4];
#pragma unroll
    for (int i = 0; i < 4; ++i) {
        float f0 = w[((size_t)o * 256 + c0 + 2 * i) * 9 + kk];
        float f1 = w[((size_t)o * 256 + c0 + 2 * i + 1) * 9 + kk];
        pk[i] = pack_bf16(f0, f1);
    }
    *(uint4*)&ws_b[(size_t)u * 8] = make_uint4(pk[0], pk[1], pk[2], pk[3]);
}

// ---------------------------------------------------------------------------
// K2: offset/mask conv (fp32).  One block per (b,ho) row; 4 waves split C 4-ways,
// each thread holds acc[27]; LDS-staged 32-channel x-slab; wave-uniform scalar
// weight loads; cross-wave reduce via LDS; sigmoid on mask channels.
// ws_off layout: [row][ch][wo], ch: 2kk=dy, 2kk+1=dx, 18+kk=mask.
// ---------------------------------------------------------------------------
__global__ __launch_bounds__(256) void offmask_kernel(
    const float* __restrict__ x, const float* __restrict__ off_w,
    const float* __restrict__ off_b, const float* __restrict__ mask_w,
    const float* __restrict__ mask_b, float* __restrict__ ws_off)
{
    __shared__ __align__(16) float slab[6912];   // [32c][3r][72] ; reused as red[4][27][64]
    const int bid = blockIdx.x;
    const int row = (bid & 7) * 32 + (bid >> 3); // XCD swizzle: contiguous rows per XCD
    const int b = row >> 6, ho = row & 63;
    const int tid = threadIdx.x;
    const int wo = tid & 63;
    const int g = __builtin_amdgcn_readfirstlane(tid >> 6);   // wave id, scalar

    float acc[27];
#pragma unroll
    for (int i = 0; i < 27; ++i) acc[i] = 0.f;

    const float* xb = x + (size_t)b * 256 * 4096;

    for (int chunk = 0; chunk < 8; ++chunk) {
        // stage 32 channels x 3 rows x 64 cols (zero-padded cols at 3 and 68)
#pragma unroll
        for (int it = 0; it < 6; ++it) {
            int i = it * 1024 + tid * 4;
            int c = i / 192, rem = i % 192;
            int r = rem >> 6, w = rem & 63;
            int hh = ho - 1 + r;
            float4 v = make_float4(0.f, 0.f, 0.f, 0.f);
            if (hh >= 0 && hh < 64)
                v = *(const float4*)&xb[(size_t)(chunk * 32 + c) * 4096 + hh * 64 + w];
            *(float4*)&slab[(c * 3 + r) * 72 + 4 + w] = v;
        }
        if (tid < 96) {
            int c = tid / 3, r = tid % 3;
            slab[(c * 3 + r) * 72 + 3] = 0.f;
            slab[(c * 3 + r) * 72 + 68] = 0.f;
        }
        __syncthreads();

#pragma unroll
        for (int cl = 0; cl < 8; ++cl) {
            int cls = g * 8 + cl;
            int cg = chunk * 32 + cls;
#pragma unroll
            for (int r = 0; r < 3; ++r) {
                const float* srow = &slab[(cls * 3 + r) * 72];
                float xm = srow[3 + wo];
                float x0 = srow[4 + wo];
                float xp = srow[5 + wo];
                const float* wop = off_w + ((size_t)cg * 3 + r) * 3;
                const float* wmp = mask_w + ((size_t)cg * 3 + r) * 3;
#pragma unroll
                for (int oc = 0; oc < 18; ++oc) {
                    const float* wp = wop + (size_t)oc * 2304;
                    acc[oc] += xm * wp[0] + x0 * wp[1] + xp * wp[2];
                }
#pragma unroll
                for (int oc = 0; oc < 9; ++oc) {
                    const float* wp = wmp + (size_t)oc * 2304;
                    acc[18 + oc] += xm * wp[0] + x0 * wp[1] + xp * wp[2];
                }
            }
        }
        __syncthreads();
    }

    // cross-wave reduction
    float* red = slab;
#pragma unroll
    for (int oc = 0; oc < 27; ++oc) red[(g * 27 + oc) * 64 + wo] = acc[oc];
    __syncthreads();
    for (int idx = tid; idx < 27 * 64; idx += 256) {
        int oc = idx >> 6, w = idx & 63;
        float s = red[(0 * 27 + oc) * 64 + w] + red[(1 * 27 + oc) * 64 + w] +
                  red[(2 * 27 + oc) * 64 + w] + red[(3 * 27 + oc) * 64 + w];
        float v;
        if (oc < 18) {
            v = s + off_b[oc];
        } else {
            float t = s + mask_b[oc - 18];
            v = 1.f / (1.f + expf(-t));
        }
        ws_off[(size_t)row * 1728 + idx] = v;
    }
}

// ---------------------------------------------------------------------------
// K3: fused deformable sampling + GEMM.
// Block = one (b,ho) row of 64 pixels; 8 waves: 0-3 producers, 4-7 consumers.
// K' = kk*256 + c, split into 36 chunks of 64.  LDS sample tile: [ku(8)][n(64)][8] bf16.
// MFMA: A = weights (M=o), B = samples (N=pixel); D col=lane&31 -> pixel (coalesced store).
// ---------------------------------------------------------------------------
__global__ __launch_bounds__(512) void deform_gemm_kernel(
    const float* __restrict__ x, const float* __restrict__ ws_off,
    const unsigned short* __restrict__ ws_b, const float* __restrict__ bias,
    float* __restrict__ out)
{
    __shared__ float offs[1728];
    __shared__ float biasl[256];
    __shared__ uint4 samp4[2][512];   // [buf][ku*64 + n] : 8 bf16 per entry, 16 KiB

    const int bid = blockIdx.x;
    const int row = (bid & 7) * 32 + (bid >> 3);
    const int b = row >> 6, ho = row & 63;
    const int tid = threadIdx.x;
    const int l = tid & 63;
    const int wid = tid >> 6;

    for (int i = tid; i < 1728; i += 512) offs[i] = ws_off[(size_t)row * 1728 + i];
    if (tid < 256) biasl[tid] = bias[tid];
    __syncthreads();

    const int p = wid;          // producer index (valid when wid < 4)
    const int cw = wid - 4;     // consumer index (valid when wid >= 4)
    const float* xb = x + (size_t)b * 256 * 4096;

    // producer per-tap state
    float w00 = 0.f, w01 = 0.f, w10 = 0.f, w11 = 0.f;
    int o00 = 0, o01 = 0, o10 = 0, o11 = 0;

    // consumer accumulators: [mt][nt] tiles of 32x32
    floatx16 acc00, acc01, acc10, acc11;
#pragma unroll
    for (int r = 0; r < 16; ++r) { acc00[r] = 0.f; acc01[r] = 0.f; acc10[r] = 0.f; acc11[r] = 0.f; }

    auto compute_tap = [&](int kk) {
        int ky = kk / 3, kx = kk - ky * 3;
        float dy = offs[(2 * kk) * 64 + l];
        float dx = offs[(2 * kk + 1) * 64 + l];
        float mk = offs[(18 + kk) * 64 + l];
        float py = (float)(ho - 1 + ky) + dy;
        float px = (float)(l - 1 + kx) + dx;
        float y0f = floorf(py), x0f = floorf(px);
        float wy1 = py - y0f, wx1 = px - x0f;
        float wy0 = 1.f - wy1, wx0 = 1.f - wx1;
        int y0 = (int)y0f, x0i = (int)x0f;
        int y1 = y0 + 1, x1i = x0i + 1;
        float vy0 = (y0 >= 0 && y0 < 64) ? 1.f : 0.f;
        float vy1 = (y1 >= 0 && y1 < 64) ? 1.f : 0.f;
        float vx0 = (x0i >= 0 && x0i < 64) ? 1.f : 0.f;
        float vx1 = (x1i >= 0 && x1i < 64) ? 1.f : 0.f;
        w00 = wy0 * wx0 * mk * vy0 * vx0;
        w01 = wy0 * wx1 * mk * vy0 * vx1;
        w10 = wy1 * wx0 * mk * vy1 * vx0;
        w11 = wy1 * wx1 * mk * vy1 * vx1;
        int yc0 = min(max(y0, 0), 63), yc1 = min(max(y1, 0), 63);
        int xc0 = min(max(x0i, 0), 63), xc1 = min(max(x1i, 0), 63);
        o00 = yc0 * 64 + xc0; o01 = yc0 * 64 + xc1;
        o10 = yc1 * 64 + xc0; o11 = yc1 * 64 + xc1;
    };

    auto sample_chunk = [&](int s) {
        const int cc = s & 3, buf = s & 1;
#pragma unroll
        for (int uu = 0; uu < 2; ++uu) {
            const int c0 = cc * 64 + p * 16 + uu * 8;
            const float* bp = xb + (size_t)c0 * 4096;
            unsigned pk[4];
#pragma unroll
            for (int i2 = 0; i2 < 4; ++i2) {
                const float* q0 = bp + (size_t)(2 * i2) * 4096;
                const float* q1 = bp + (size_t)(2 * i2 + 1) * 4096;
                float v0 = w00 * q0[o00] + w01 * q0[o01] + w10 * q0[o10] + w11 * q0[o11];
                float v1 = w00 * q1[o00] + w01 * q1[o01] + w10 * q1[o10] + w11 * q1[o11];
                pk[i2] = pack_bf16(v0, v1);
            }
            samp4[buf][(p * 2 + uu) * 64 + l] = make_uint4(pk[0], pk[1], pk[2], pk[3]);
        }
    };

    auto do_mfma = [&](int t) {
        const int kk = t >> 2, cc = t & 3, buf = t & 1;
        const int kub = kk * 32 + cc * 8;        // global K'/8 base of this chunk
        const int lan = l & 31, h = l >> 5;
        const uint4* wb4 = (const uint4*)ws_b;
#pragma unroll
        for (int ks = 0; ks < 4; ++ks) {
            const int ku = kub + ks * 2 + h;
            uint4 ua0 = wb4[((size_t)(cw * 2 + 0) * 288 + ku) * 32 + lan];
            uint4 ua1 = wb4[((size_t)(cw * 2 + 1) * 288 + ku) * 32 + lan];
            uint4 ub0 = samp4[buf][(ks * 2 + h) * 64 + lan];
            uint4 ub1 = samp4[buf][(ks * 2 + h) * 64 + 32 + lan];
            short8 a0, a1, b0, b1;
            __builtin_memcpy(&a0, &ua0, 16);
            __builtin_memcpy(&a1, &ua1, 16);
            __builtin_memcpy(&b0, &ub0, 16);
            __builtin_memcpy(&b1, &ub1, 16);
            acc00 = __builtin_amdgcn_mfma_f32_32x32x16_bf16(a0, b0, acc00, 0, 0, 0);
            acc01 = __builtin_amdgcn_mfma_f32_32x32x16_bf16(a0, b1, acc01, 0, 0, 0);
            acc10 = __builtin_amdgcn_mfma_f32_32x32x16_bf16(a1, b0, acc10, 0, 0, 0);
            acc11 = __builtin_amdgcn_mfma_f32_32x32x16_bf16(a1, b1, acc11, 0, 0, 0);
        }
    };

    if (wid < 4) { compute_tap(0); sample_chunk(0); }
    __syncthreads();

    for (int t = 0; t < 36; ++t) {
        if (wid < 4) {
            int s = t + 1;
            if (s < 36) {
                if ((s & 3) == 0) compute_tap(s >> 2);
                sample_chunk(s);
            }
        } else {
            do_mfma(t);
        }
        __syncthreads();
    }

    if (wid >= 4) {
        const int lan = l & 31, h = l >> 5;
#pragma unroll
        for (int mi = 0; mi < 2; ++mi) {
#pragma unroll
            for (int nt = 0; nt < 2; ++nt) {
#pragma unroll
                for (int r = 0; r < 16; ++r) {
                    int o = (cw * 2 + mi) * 32 + (r & 3) + 8 * (r >> 2) + 4 * h;
                    int woo = nt * 32 + lan;
                    float v;
                    if (mi == 0) v = (nt == 0) ? acc00[r] : acc01[r];
                    else         v = (nt == 0) ? acc10[r] : acc11[r];
                    out[(((size_t)b * 256 + o) * 64 + ho) * 64 + woo] = v + biasl[o];
                }
            }
        }
    }
}

extern "C" void kernel_launch(void* const* d_in, const int* in_sizes, int n_in,
                              void* d_out, int out_size, void* d_ws, size_t ws_size,
                              hipStream_t stream) {
    const float* x      = (const float*)d_in[0];
    const float* weight = (const float*)d_in[1];
    const float* bias   = (const float*)d_in[2];
    const float* off_w  = (const float*)d_in[3];
    const float* off_b  = (const float*)d_in[4];
    const float* mask_w = (const float*)d_in[5];
    const float* mask_b = (const float*)d_in[6];
    float* out = (float*)d_out;

    float* ws_off = (float*)d_ws;                                   // 1,769,472 B
    unsigned short* ws_b = (unsigned short*)((char*)d_ws + 1769472); // 1,179,648 B

    hipLaunchKernelGGL(weight_pack_kernel, dim3(288), dim3(256), 0, stream, weight, ws_b);
    hipLaunchKernelGGL(offmask_kernel, dim3(256), dim3(256), 0, stream,
                       x, off_w, off_b, mask_w, mask_b, ws_off);
    hipLaunchKernelGGL(deform_gemm_kernel, dim3(256), dim3(512), 0, stream,
                       x, ws_off, ws_b, bias, out);
}

// Round 2
// 241.159 us; speedup vs baseline: 2.4581x; 2.4581x over previous
//
#include <hip/hip_runtime.h>
#include <hip/hip_bf16.h>
#include <string.h>

// DeformableConv2d: B=4, C=256, O=256, H=W=64, K=3, pad=1, stride=1
// Plan:
//   K1 weight_pack : fp32 weight (O,C,3,3) -> bf16 A-frag [o/32][K'/8][o&31][8], K'=kk*256+c
//                    + offmask weights -> f16 A-frag [ku(288)][oc(32 rows, 27 used)][8]
//   K2 offmask_mfma: f16 MFMA GEMM  C[27 x 16384] = W[27 x 2304] * im2col(x)
//   K3 deform_gemm : producer waves bilinear-sample -> LDS bf16 B-tile; consumer waves
//                    32x32x16 bf16 MFMA  (unchanged from round 1, verified correct)
// Workspace: ws_off = 256*27*64 f32 (1769472 B), ws_b = 256*2304 bf16 (1179648 B),
//            ws_a2 = 288*32*8 f16 (147456 B)  => 3096576 B total.

typedef __attribute__((ext_vector_type(8))) short short8;
typedef __attribute__((ext_vector_type(8))) _Float16 half8;
typedef __attribute__((ext_vector_type(16))) float floatx16;

__device__ __forceinline__ unsigned bfbits(float f) {
    unsigned u;
    __builtin_memcpy(&u, &f, 4);
    return (u + 0x7fffu + ((u >> 16) & 1u)) >> 16;   // RNE f32->bf16
}
__device__ __forceinline__ unsigned pack_bf16(float lo, float hi) {
    return bfbits(lo) | (bfbits(hi) << 16);
}
__device__ __forceinline__ unsigned pack_f16(float lo, float hi) {
    _Float16 a = (_Float16)lo, b = (_Float16)hi;
    unsigned short ua, ub;
    __builtin_memcpy(&ua, &a, 2);
    __builtin_memcpy(&ub, &b, 2);
    return (unsigned)ua | ((unsigned)ub << 16);
}

// ---------------------------------------------------------------------------
// K1: weight pack.  gid < 73728: main-conv bf16 A-frag; else offmask f16 A-frag.
// ---------------------------------------------------------------------------
__global__ __launch_bounds__(256) void weight_pack_kernel(
    const float* __restrict__ w, const float* __restrict__ off_w,
    const float* __restrict__ mask_w,
    unsigned short* __restrict__ ws_b, unsigned short* __restrict__ ws_a2)
{
    int gid = blockIdx.x * 256 + threadIdx.x;
    if (gid < 73728) {
        int u = gid;
        int no = u & 31;
        int t2 = u >> 5;
        int ku = t2 % 288;
        int nt = t2 / 288;
        int o  = nt * 32 + no;
        int kk = ku >> 5;
        int c0 = (ku & 31) * 8;
        unsigned pk[4];
#pragma unroll
        for (int i = 0; i < 4; ++i) {
            float f0 = w[((size_t)o * 256 + c0 + 2 * i) * 9 + kk];
            float f1 = w[((size_t)o * 256 + c0 + 2 * i + 1) * 9 + kk];
            pk[i] = pack_bf16(f0, f1);
        }
        *(uint4*)&ws_b[(size_t)u * 8] = make_uint4(pk[0], pk[1], pk[2], pk[3]);
    } else {
        int e = gid - 73728;          // 0..9215
        int lan = e & 31;             // oc row
        int ku = e >> 5;              // 0..287
        int kk = ku >> 5;             // 0..8
        int c0 = (ku & 31) * 8;
        int o = lan;
        float f[8];
#pragma unroll
        for (int j = 0; j < 8; ++j) {
            int c = c0 + j;
            float v = 0.f;
            if (o < 18)      v = off_w[((size_t)o * 256 + c) * 9 + kk];
            else if (o < 27) v = mask_w[((size_t)(o - 18) * 256 + c) * 9 + kk];
            f[j] = v;
        }
        unsigned pk[4];
#pragma unroll
        for (int i = 0; i < 4; ++i) pk[i] = pack_f16(f[2 * i], f[2 * i + 1]);
        *(uint4*)&ws_a2[(size_t)e * 8] = make_uint4(pk[0], pk[1], pk[2], pk[3]);
    }
}

// ---------------------------------------------------------------------------
// K2: offset/mask conv via f16 MFMA.  One block per (b,ho) row of 64 pixels.
// K' = kk*256 + c; 9 tap-chunks of 256 K'.  B-tile LDS: [ku(32)][n(64)][8] f16,
// double-buffered.  8 waves = 2 n-tiles x 4 K-quarters; LDS partial-C reduce;
// bias + sigmoid epilogue -> ws_off[row][27][64].
// ---------------------------------------------------------------------------
__global__ __launch_bounds__(512) void offmask_mfma_kernel(
    const float* __restrict__ x, const unsigned short* __restrict__ ws_a2,
    const float* __restrict__ off_b, const float* __restrict__ mask_b,
    float* __restrict__ ws_off)
{
    __shared__ uint4 bufB[2][2048];   // 64 KiB; aliased as red[] after last chunk
    const int bid = blockIdx.x;
    const int row = (bid & 7) * 32 + (bid >> 3);
    const int b = row >> 6, ho = row & 63;
    const int tid = threadIdx.x;
    const int l = tid & 63;
    const int w = tid >> 6;
    const int lan = l & 31, h = l >> 5;
    const float* xb = x + (size_t)b * 256 * 4096;

    floatx16 acc;
#pragma unroll
    for (int r = 0; r < 16; ++r) acc[r] = 0.f;

    const int n = l;                 // pixel within row
    const int ku0 = w;               // 0..7

    auto build = [&](int kk) {
        int ky = kk / 3, kx = kk - ky * 3;
        int hh = ho - 1 + ky;
        int px = n - 1 + kx;
        bool vh = (hh >= 0 && hh < 64);
        bool vx = (px >= 0 && px < 64);
        int base = hh * 64 + px;
        int buf = kk & 1;
#pragma unroll
        for (int j = 0; j < 4; ++j) {
            int ku = ku0 + 8 * j;
            int c0 = ku * 8;
            float v[8];
#pragma unroll
            for (int jj = 0; jj < 8; ++jj) {
                float t = 0.f;
                if (vh && vx) t = xb[(size_t)(c0 + jj) * 4096 + base];
                v[jj] = t;
            }
            unsigned pk[4];
#pragma unroll
            for (int i = 0; i < 4; ++i) pk[i] = pack_f16(v[2 * i], v[2 * i + 1]);
            bufB[buf][ku * 64 + n] = make_uint4(pk[0], pk[1], pk[2], pk[3]);
        }
    };

    const int ntile = w >> 2, kq = w & 3;
    auto domfma = [&](int kk) {
        int buf = kk & 1;
        const uint4* a4 = (const uint4*)ws_a2;
#pragma unroll
        for (int s4 = 0; s4 < 4; ++s4) {
            int s = kq * 4 + s4;         // K-step 0..15 within chunk
            int kul = s * 2 + h;         // local ku 0..31
            uint4 ua = a4[(size_t)(kk * 32 + kul) * 32 + lan];
            uint4 ub = bufB[buf][kul * 64 + ntile * 32 + lan];
            half8 a, bb;
            __builtin_memcpy(&a, &ua, 16);
            __builtin_memcpy(&bb, &ub, 16);
            acc = __builtin_amdgcn_mfma_f32_32x32x16_f16(a, bb, acc, 0, 0, 0);
        }
    };

    build(0);
    __syncthreads();
    for (int kk = 0; kk < 9; ++kk) {
        if (kk + 1 < 9) build(kk + 1);
        domfma(kk);
        __syncthreads();
    }

    // cross-wave partial-C reduction (4 K-quarters per n-tile)
    float* red = (float*)bufB;        // 8 waves x 64 lanes x 16 = 32 KiB
#pragma unroll
    for (int r = 0; r < 16; ++r) red[(w * 64 + l) * 16 + r] = acc[r];
    __syncthreads();
    for (int idx = tid; idx < 27 * 64; idx += 512) {
        int oc = idx >> 6, wo = idx & 63;
        int nt2 = wo >> 5, nn = wo & 31;
        int h2 = (oc >> 2) & 1;
        int r = (oc & 3) | ((oc >> 3) << 2);
        int lane2 = nn + 32 * h2;
        float s = 0.f;
#pragma unroll
        for (int kq2 = 0; kq2 < 4; ++kq2)
            s += red[((nt2 * 4 + kq2) * 64 + lane2) * 16 + r];
        float v;
        if (oc < 18) {
            v = s + off_b[oc];
        } else {
            float t = s + mask_b[oc - 18];
            v = 1.f / (1.f + expf(-t));
        }
        ws_off[(size_t)row * 1728 + idx] = v;
    }
}

// ---------------------------------------------------------------------------
// K3: fused deformable sampling + GEMM (unchanged, verified round 1).
// ---------------------------------------------------------------------------
__global__ __launch_bounds__(512) void deform_gemm_kernel(
    const float* __restrict__ x, const float* __restrict__ ws_off,
    const unsigned short* __restrict__ ws_b, const float* __restrict__ bias,
    float* __restrict__ out)
{
    __shared__ float offs[1728];
    __shared__ float biasl[256];
    __shared__ uint4 samp4[2][512];   // [buf][ku*64 + n] : 8 bf16 per entry, 16 KiB

    const int bid = blockIdx.x;
    const int row = (bid & 7) * 32 + (bid >> 3);
    const int b = row >> 6, ho = row & 63;
    const int tid = threadIdx.x;
    const int l = tid & 63;
    const int wid = tid >> 6;

    for (int i = tid; i < 1728; i += 512) offs[i] = ws_off[(size_t)row * 1728 + i];
    if (tid < 256) biasl[tid] = bias[tid];
    __syncthreads();

    const int p = wid;          // producer index (valid when wid < 4)
    const int cw = wid - 4;     // consumer index (valid when wid >= 4)
    const float* xb = x + (size_t)b * 256 * 4096;

    float w00 = 0.f, w01 = 0.f, w10 = 0.f, w11 = 0.f;
    int o00 = 0, o01 = 0, o10 = 0, o11 = 0;

    floatx16 acc00, acc01, acc10, acc11;
#pragma unroll
    for (int r = 0; r < 16; ++r) { acc00[r] = 0.f; acc01[r] = 0.f; acc10[r] = 0.f; acc11[r] = 0.f; }

    auto compute_tap = [&](int kk) {
        int ky = kk / 3, kx = kk - ky * 3;
        float dy = offs[(2 * kk) * 64 + l];
        float dx = offs[(2 * kk + 1) * 64 + l];
        float mk = offs[(18 + kk) * 64 + l];
        float py = (float)(ho - 1 + ky) + dy;
        float px = (float)(l - 1 + kx) + dx;
        float y0f = floorf(py), x0f = floorf(px);
        float wy1 = py - y0f, wx1 = px - x0f;
        float wy0 = 1.f - wy1, wx0 = 1.f - wx1;
        int y0 = (int)y0f, x0i = (int)x0f;
        int y1 = y0 + 1, x1i = x0i + 1;
        float vy0 = (y0 >= 0 && y0 < 64) ? 1.f : 0.f;
        float vy1 = (y1 >= 0 && y1 < 64) ? 1.f : 0.f;
        float vx0 = (x0i >= 0 && x0i < 64) ? 1.f : 0.f;
        float vx1 = (x1i >= 0 && x1i < 64) ? 1.f : 0.f;
        w00 = wy0 * wx0 * mk * vy0 * vx0;
        w01 = wy0 * wx1 * mk * vy0 * vx1;
        w10 = wy1 * wx0 * mk * vy1 * vx0;
        w11 = wy1 * wx1 * mk * vy1 * vx1;
        int yc0 = min(max(y0, 0), 63), yc1 = min(max(y1, 0), 63);
        int xc0 = min(max(x0i, 0), 63), xc1 = min(max(x1i, 0), 63);
        o00 = yc0 * 64 + xc0; o01 = yc0 * 64 + xc1;
        o10 = yc1 * 64 + xc0; o11 = yc1 * 64 + xc1;
    };

    auto sample_chunk = [&](int s) {
        const int cc = s & 3, buf = s & 1;
#pragma unroll
        for (int uu = 0; uu < 2; ++uu) {
            const int c0 = cc * 64 + p * 16 + uu * 8;
            const float* bp = xb + (size_t)c0 * 4096;
            unsigned pk[4];
#pragma unroll
            for (int i2 = 0; i2 < 4; ++i2) {
                const float* q0 = bp + (size_t)(2 * i2) * 4096;
                const float* q1 = bp + (size_t)(2 * i2 + 1) * 4096;
                float v0 = w00 * q0[o00] + w01 * q0[o01] + w10 * q0[o10] + w11 * q0[o11];
                float v1 = w00 * q1[o00] + w01 * q1[o01] + w10 * q1[o10] + w11 * q1[o11];
                pk[i2] = pack_bf16(v0, v1);
            }
            samp4[buf][(p * 2 + uu) * 64 + l] = make_uint4(pk[0], pk[1], pk[2], pk[3]);
        }
    };

    auto do_mfma = [&](int t) {
        const int buf = t & 1;
        const int kk = t >> 2, cc = t & 3;
        const int kub = kk * 32 + cc * 8;
        const int lan = l & 31, h = l >> 5;
        const uint4* wb4 = (const uint4*)ws_b;
#pragma unroll
        for (int ks = 0; ks < 4; ++ks) {
            const int ku = kub + ks * 2 + h;
            uint4 ua0 = wb4[((size_t)(cw * 2 + 0) * 288 + ku) * 32 + lan];
            uint4 ua1 = wb4[((size_t)(cw * 2 + 1) * 288 + ku) * 32 + lan];
            uint4 ub0 = samp4[buf][(ks * 2 + h) * 64 + lan];
            uint4 ub1 = samp4[buf][(ks * 2 + h) * 64 + 32 + lan];
            short8 a0, a1, b0, b1;
            __builtin_memcpy(&a0, &ua0, 16);
            __builtin_memcpy(&a1, &ua1, 16);
            __builtin_memcpy(&b0, &ub0, 16);
            __builtin_memcpy(&b1, &ub1, 16);
            acc00 = __builtin_amdgcn_mfma_f32_32x32x16_bf16(a0, b0, acc00, 0, 0, 0);
            acc01 = __builtin_amdgcn_mfma_f32_32x32x16_bf16(a0, b1, acc01, 0, 0, 0);
            acc10 = __builtin_amdgcn_mfma_f32_32x32x16_bf16(a1, b0, acc10, 0, 0, 0);
            acc11 = __builtin_amdgcn_mfma_f32_32x32x16_bf16(a1, b1, acc11, 0, 0, 0);
        }
    };

    if (wid < 4) { compute_tap(0); sample_chunk(0); }
    __syncthreads();

    for (int t = 0; t < 36; ++t) {
        if (wid < 4) {
            int s = t + 1;
            if (s < 36) {
                if ((s & 3) == 0) compute_tap(s >> 2);
                sample_chunk(s);
            }
        } else {
            do_mfma(t);
        }
        __syncthreads();
    }

    if (wid >= 4) {
        const int lan = l & 31, h = l >> 5;
#pragma unroll
        for (int mi = 0; mi < 2; ++mi) {
#pragma unroll
            for (int nt = 0; nt < 2; ++nt) {
#pragma unroll
                for (int r = 0; r < 16; ++r) {
                    int o = (cw * 2 + mi) * 32 + (r & 3) + 8 * (r >> 2) + 4 * h;
                    int woo = nt * 32 + lan;
                    float v;
                    if (mi == 0) v = (nt == 0) ? acc00[r] : acc01[r];
                    else         v = (nt == 0) ? acc10[r] : acc11[r];
                    out[(((size_t)b * 256 + o) * 64 + ho) * 64 + woo] = v + biasl[o];
                }
            }
        }
    }
}

extern "C" void kernel_launch(void* const* d_in, const int* in_sizes, int n_in,
                              void* d_out, int out_size, void* d_ws, size_t ws_size,
                              hipStream_t stream) {
    const float* x      = (const float*)d_in[0];
    const float* weight = (const float*)d_in[1];
    const float* bias   = (const float*)d_in[2];
    const float* off_w  = (const float*)d_in[3];
    const float* off_b  = (const float*)d_in[4];
    const float* mask_w = (const float*)d_in[5];
    const float* mask_b = (const float*)d_in[6];
    float* out = (float*)d_out;

    float* ws_off = (float*)d_ws;                                      // 1,769,472 B
    unsigned short* ws_b  = (unsigned short*)((char*)d_ws + 1769472);  // 1,179,648 B
    unsigned short* ws_a2 = (unsigned short*)((char*)d_ws + 2949120);  //   147,456 B

    hipLaunchKernelGGL(weight_pack_kernel, dim3(324), dim3(256), 0, stream,
                       weight, off_w, mask_w, ws_b, ws_a2);
    hipLaunchKernelGGL(offmask_mfma_kernel, dim3(256), dim3(512), 0, stream,
                       x, ws_a2, off_b, mask_b, ws_off);
    hipLaunchKernelGGL(deform_gemm_kernel, dim3(256), dim3(512), 0, stream,
                       x, ws_off, ws_b, bias, out);
}

// Round 4
// 239.817 us; speedup vs baseline: 2.4719x; 1.0056x over previous
//
#include <hip/hip_runtime.h>
#include <hip/hip_bf16.h>
#include <string.h>

// DeformableConv2d: B=4, C=256, O=256, H=W=64, K=3, pad=1, stride=1
// Round 4: re-anchor on round-2-verified skeletons.
//   K1 weight_pack : LDS-transpose pack, coalesced reads (verified r3 math).
//   K2 offmask_mfma: verbatim round-2 (verified) f16 MFMA conv.
//   K3 deform_gemm : round-2 verified 2-barrier skeleton, widened to 16 waves
//                    (8 producers / 8 consumers) for 2.5x occupancy.
// Workspace: ws_off 1769472 B | ws_b 1179648 B | ws_a2 147456 B = 3096576 B.

typedef __attribute__((ext_vector_type(8))) short short8;
typedef __attribute__((ext_vector_type(8))) _Float16 half8;
typedef __attribute__((ext_vector_type(16))) float floatx16;

__device__ __forceinline__ unsigned bfbits(float f) {
    unsigned u;
    __builtin_memcpy(&u, &f, 4);
    return (u + 0x7fffu + ((u >> 16) & 1u)) >> 16;   // RNE f32->bf16
}
__device__ __forceinline__ unsigned pack_bf16(float lo, float hi) {
    return bfbits(lo) | (bfbits(hi) << 16);
}
__device__ __forceinline__ unsigned pack_f16(float lo, float hi) {
    _Float16 a = (_Float16)lo, b = (_Float16)hi;
    unsigned short ua, ub;
    __builtin_memcpy(&ua, &a, 2);
    __builtin_memcpy(&ub, &b, 2);
    return (unsigned)ua | ((unsigned)ub << 16);
}

// ---------------------------------------------------------------------------
// K1: weight pack.
//  blocks [0,64): main weights via LDS transpose (coalesced float4 stage).
//  blocks [64,100): offmask f16 A-frag.
// ---------------------------------------------------------------------------
__global__ __launch_bounds__(256) void weight_pack_kernel(
    const float* __restrict__ w, const float* __restrict__ off_w,
    const float* __restrict__ mask_w,
    unsigned short* __restrict__ ws_b, unsigned short* __restrict__ ws_a2)
{
    __shared__ float slab[32 * 289];
    const int bid = blockIdx.x;
    const int tid = threadIdx.x;

    if (bid < 64) {
        const int nt = bid >> 3, cb = bid & 7;
        const float* wbase = w + (size_t)nt * 32 * 2304 + cb * 288;
#pragma unroll
        for (int i = 0; i < 9; ++i) {
            int idx = i * 256 + tid;               // 0..2303
            int o = idx / 72, f4 = idx % 72;
            float4 v = *(const float4*)&wbase[(size_t)o * 2304 + f4 * 4];
            slab[o * 289 + f4 * 4 + 0] = v.x;
            slab[o * 289 + f4 * 4 + 1] = v.y;
            slab[o * 289 + f4 * 4 + 2] = v.z;
            slab[o * 289 + f4 * 4 + 3] = v.w;
        }
        __syncthreads();
#pragma unroll
        for (int pass = 0; pass < 5; ++pass) {
            int rid = pass * 8 + (tid >> 5);
            if (rid < 36) {
                int kk = rid >> 2, q = rid & 3;
                int no = tid & 31;
                unsigned pk[4];
#pragma unroll
                for (int i = 0; i < 4; ++i) {
                    float f0 = slab[no * 289 + (q * 8 + 2 * i) * 9 + kk];
                    float f1 = slab[no * 289 + (q * 8 + 2 * i + 1) * 9 + kk];
                    pk[i] = pack_bf16(f0, f1);
                }
                size_t u = ((size_t)nt * 288 + kk * 32 + cb * 4 + q) * 32 + no;
                *(uint4*)&ws_b[u * 8] = make_uint4(pk[0], pk[1], pk[2], pk[3]);
            }
        }
    } else {
        int e = (bid - 64) * 256 + tid;       // 0..9215
        int lan = e & 31;                     // oc row
        int ku = e >> 5;                      // 0..287
        int kk = ku >> 5;
        int c0 = (ku & 31) * 8;
        int o = lan;
        float f[8];
#pragma unroll
        for (int j = 0; j < 8; ++j) {
            int c = c0 + j;
            float v = 0.f;
            if (o < 18)      v = off_w[((size_t)o * 256 + c) * 9 + kk];
            else if (o < 27) v = mask_w[((size_t)(o - 18) * 256 + c) * 9 + kk];
            f[j] = v;
        }
        unsigned pk[4];
#pragma unroll
        for (int i = 0; i < 4; ++i) pk[i] = pack_f16(f[2 * i], f[2 * i + 1]);
        *(uint4*)&ws_a2[(size_t)e * 8] = make_uint4(pk[0], pk[1], pk[2], pk[3]);
    }
}

// ---------------------------------------------------------------------------
// K2: offset/mask conv via f16 MFMA (verbatim round-2, verified).
// ---------------------------------------------------------------------------
__global__ __launch_bounds__(512) void offmask_mfma_kernel(
    const float* __restrict__ x, const unsigned short* __restrict__ ws_a2,
    const float* __restrict__ off_b, const float* __restrict__ mask_b,
    float* __restrict__ ws_off)
{
    __shared__ uint4 bufB[2][2048];   // 64 KiB; aliased as red[] in epilogue
    const int bid = blockIdx.x;
    const int row = (bid & 7) * 32 + (bid >> 3);
    const int b = row >> 6, ho = row & 63;
    const int tid = threadIdx.x;
    const int l = tid & 63;
    const int w = tid >> 6;
    const int lan = l & 31, h = l >> 5;
    const float* xb = x + (size_t)b * 256 * 4096;

    floatx16 acc;
#pragma unroll
    for (int r = 0; r < 16; ++r) acc[r] = 0.f;

    const int n = l;                 // pixel within row
    const int ku0 = w;               // 0..7

    auto build = [&](int kk) {
        int ky = kk / 3, kx = kk - ky * 3;
        int hh = ho - 1 + ky;
        int px = n - 1 + kx;
        bool vh = (hh >= 0 && hh < 64);
        bool vx = (px >= 0 && px < 64);
        int base = hh * 64 + px;
        int buf = kk & 1;
#pragma unroll
        for (int j = 0; j < 4; ++j) {
            int ku = ku0 + 8 * j;
            int c0 = ku * 8;
            float v[8];
#pragma unroll
            for (int jj = 0; jj < 8; ++jj) {
                float t = 0.f;
                if (vh && vx) t = xb[(size_t)(c0 + jj) * 4096 + base];
                v[jj] = t;
            }
            unsigned pk[4];
#pragma unroll
            for (int i = 0; i < 4; ++i) pk[i] = pack_f16(v[2 * i], v[2 * i + 1]);
            bufB[buf][ku * 64 + n] = make_uint4(pk[0], pk[1], pk[2], pk[3]);
        }
    };

    const int ntile = w >> 2, kq = w & 3;
    auto domfma = [&](int kk) {
        int buf = kk & 1;
        const uint4* a4 = (const uint4*)ws_a2;
#pragma unroll
        for (int s4 = 0; s4 < 4; ++s4) {
            int s = kq * 4 + s4;         // K-step 0..15 within chunk
            int kul = s * 2 + h;         // local ku 0..31
            uint4 ua = a4[(size_t)(kk * 32 + kul) * 32 + lan];
            uint4 ub = bufB[buf][kul * 64 + ntile * 32 + lan];
            half8 a, bb;
            __builtin_memcpy(&a, &ua, 16);
            __builtin_memcpy(&bb, &ub, 16);
            acc = __builtin_amdgcn_mfma_f32_32x32x16_f16(a, bb, acc, 0, 0, 0);
        }
    };

    build(0);
    __syncthreads();
    for (int kk = 0; kk < 9; ++kk) {
        if (kk + 1 < 9) build(kk + 1);
        domfma(kk);
        __syncthreads();
    }

    // cross-wave partial-C reduction (4 K-quarters per n-tile)
    float* red = (float*)bufB;        // 8 waves x 64 lanes x 16 = 32 KiB
#pragma unroll
    for (int r = 0; r < 16; ++r) red[(w * 64 + l) * 16 + r] = acc[r];
    __syncthreads();
    for (int idx = tid; idx < 27 * 64; idx += 512) {
        int oc = idx >> 6, wo = idx & 63;
        int nt2 = wo >> 5, nn = wo & 31;
        int h2 = (oc >> 2) & 1;
        int r = (oc & 3) | ((oc >> 3) << 2);
        int lane2 = nn + 32 * h2;
        float s = 0.f;
#pragma unroll
        for (int kq2 = 0; kq2 < 4; ++kq2)
            s += red[((nt2 * 4 + kq2) * 64 + lane2) * 16 + r];
        float v;
        if (oc < 18) {
            v = s + off_b[oc];
        } else {
            float t = s + mask_b[oc - 18];
            v = 1.f / (1.f + expf(-t));
        }
        ws_off[(size_t)row * 1728 + idx] = v;
    }
}

// ---------------------------------------------------------------------------
// K3: fused deformable sampling + GEMM.  Round-2 verified 2-barrier skeleton,
// widened: 16 waves = 8 producers (unit wid, channels wid*8) + 8 consumers
// (m-tile wid-8, 2 n-tiles).  Unit<->channel map identical to round 2.
// ---------------------------------------------------------------------------
__global__ __launch_bounds__(1024) void deform_gemm_kernel(
    const float* __restrict__ x, const float* __restrict__ ws_off,
    const unsigned short* __restrict__ ws_b, const float* __restrict__ bias,
    float* __restrict__ out)
{
    __shared__ float offs[1728];
    __shared__ float biasl[256];
    __shared__ uint4 samp4[2][512];   // [buf][unit*64 + n] : 8 bf16 per entry

    const int bid = blockIdx.x;
    const int row = (bid & 7) * 32 + (bid >> 3);
    const int b = row >> 6, ho = row & 63;
    const int tid = threadIdx.x;
    const int l = tid & 63;
    const int wid = tid >> 6;          // 0..15

    for (int i = tid; i < 1728; i += 1024) offs[i] = ws_off[(size_t)row * 1728 + i];
    if (tid < 256) biasl[tid] = bias[tid];
    __syncthreads();

    const int p = wid;          // producer unit (valid when wid < 8)
    const int cw = wid - 8;     // consumer m-tile (valid when wid >= 8)
    const float* xb = x + (size_t)b * 256 * 4096;

    float w00 = 0.f, w01 = 0.f, w10 = 0.f, w11 = 0.f;
    int o00 = 0, o01 = 0, o10 = 0, o11 = 0;

    floatx16 acc0, acc1;
#pragma unroll
    for (int r = 0; r < 16; ++r) { acc0[r] = 0.f; acc1[r] = 0.f; }

    auto compute_tap = [&](int kk) {
        int ky = kk / 3, kx = kk - ky * 3;
        float dy = offs[(2 * kk) * 64 + l];
        float dx = offs[(2 * kk + 1) * 64 + l];
        float mk = offs[(18 + kk) * 64 + l];
        float py = (float)(ho - 1 + ky) + dy;
        float px = (float)(l - 1 + kx) + dx;
        float y0f = floorf(py), x0f = floorf(px);
        float wy1 = py - y0f, wx1 = px - x0f;
        float wy0 = 1.f - wy1, wx0 = 1.f - wx1;
        int y0 = (int)y0f, x0i = (int)x0f;
        int y1 = y0 + 1, x1i = x0i + 1;
        float vy0 = (y0 >= 0 && y0 < 64) ? 1.f : 0.f;
        float vy1 = (y1 >= 0 && y1 < 64) ? 1.f : 0.f;
        float vx0 = (x0i >= 0 && x0i < 64) ? 1.f : 0.f;
        float vx1 = (x1i >= 0 && x1i < 64) ? 1.f : 0.f;
        w00 = wy0 * wx0 * mk * vy0 * vx0;
        w01 = wy0 * wx1 * mk * vy0 * vx1;
        w10 = wy1 * wx0 * mk * vy1 * vx0;
        w11 = wy1 * wx1 * mk * vy1 * vx1;
        int yc0 = min(max(y0, 0), 63), yc1 = min(max(y1, 0), 63);
        int xc0 = min(max(x0i, 0), 63), xc1 = min(max(x1i, 0), 63);
        o00 = yc0 * 64 + xc0; o01 = yc0 * 64 + xc1;
        o10 = yc1 * 64 + xc0; o11 = yc1 * 64 + xc1;
    };

    auto sample_chunk = [&](int s) {
        const int cc = s & 3, buf = s & 1;
        const int c0 = cc * 64 + p * 8;
        const float* bp = xb + (size_t)c0 * 4096;
        unsigned pk[4];
#pragma unroll
        for (int i2 = 0; i2 < 4; ++i2) {
            const float* q0 = bp + (size_t)(2 * i2) * 4096;
            const float* q1 = bp + (size_t)(2 * i2 + 1) * 4096;
            float v0 = w00 * q0[o00] + w01 * q0[o01] + w10 * q0[o10] + w11 * q0[o11];
            float v1 = w00 * q1[o00] + w01 * q1[o01] + w10 * q1[o10] + w11 * q1[o11];
            pk[i2] = pack_bf16(v0, v1);
        }
        samp4[buf][p * 64 + l] = make_uint4(pk[0], pk[1], pk[2], pk[3]);
    };

    auto do_mfma = [&](int t) {
        const int buf = t & 1;
        const int kk = t >> 2, cc = t & 3;
        const int kub = kk * 32 + cc * 8;
        const int lan = l & 31, h = l >> 5;
        const uint4* wb4 = (const uint4*)ws_b;
#pragma unroll
        for (int ks = 0; ks < 4; ++ks) {
            const int ku = kub + ks * 2 + h;
            uint4 ua0 = wb4[((size_t)cw * 288 + ku) * 32 + lan];
            uint4 ub0 = samp4[buf][(ks * 2 + h) * 64 + lan];
            uint4 ub1 = samp4[buf][(ks * 2 + h) * 64 + 32 + lan];
            short8 a0, b0, b1;
            __builtin_memcpy(&a0, &ua0, 16);
            __builtin_memcpy(&b0, &ub0, 16);
            __builtin_memcpy(&b1, &ub1, 16);
            acc0 = __builtin_amdgcn_mfma_f32_32x32x16_bf16(a0, b0, acc0, 0, 0, 0);
            acc1 = __builtin_amdgcn_mfma_f32_32x32x16_bf16(a0, b1, acc1, 0, 0, 0);
        }
    };

    if (wid < 8) { compute_tap(0); sample_chunk(0); }
    __syncthreads();

    for (int t = 0; t < 36; ++t) {
        if (wid < 8) {
            int s = t + 1;
            if (s < 36) {
                if ((s & 3) == 0) compute_tap(s >> 2);
                sample_chunk(s);
            }
        } else {
            do_mfma(t);
        }
        __syncthreads();
    }

    if (wid >= 8) {
        const int lan = l & 31, h = l >> 5;
#pragma unroll
        for (int nt = 0; nt < 2; ++nt) {
#pragma unroll
            for (int r = 0; r < 16; ++r) {
                int o = cw * 32 + (r & 3) + 8 * (r >> 2) + 4 * h;
                int woo = nt * 32 + lan;
                float v = (nt == 0) ? acc0[r] : acc1[r];
                out[(((size_t)b * 256 + o) * 64 + ho) * 64 + woo] = v + biasl[o];
            }
        }
    }
}

extern "C" void kernel_launch(void* const* d_in, const int* in_sizes, int n_in,
                              void* d_out, int out_size, void* d_ws, size_t ws_size,
                              hipStream_t stream) {
    const float* x      = (const float*)d_in[0];
    const float* weight = (const float*)d_in[1];
    const float* bias   = (const float*)d_in[2];
    const float* off_w  = (const float*)d_in[3];
    const float* off_b  = (const float*)d_in[4];
    const float* mask_w = (const float*)d_in[5];
    const float* mask_b = (const float*)d_in[6];
    float* out = (float*)d_out;

    float* ws_off = (float*)d_ws;                                      // 1,769,472 B
    unsigned short* ws_b  = (unsigned short*)((char*)d_ws + 1769472);  // 1,179,648 B
    unsigned short* ws_a2 = (unsigned short*)((char*)d_ws + 2949120);  //   147,456 B

    hipLaunchKernelGGL(weight_pack_kernel, dim3(100), dim3(256), 0, stream,
                       weight, off_w, mask_w, ws_b, ws_a2);
    hipLaunchKernelGGL(offmask_mfma_kernel, dim3(256), dim3(512), 0, stream,
                       x, ws_a2, off_b, mask_b, ws_off);
    hipLaunchKernelGGL(deform_gemm_kernel, dim3(256), dim3(1024), 0, stream,
                       x, ws_off, ws_b, bias, out);
}

// Round 5
// 235.229 us; speedup vs baseline: 2.5201x; 1.0195x over previous
//
#include <hip/hip_runtime.h>
#include <hip/hip_bf16.h>
#include <string.h>

// DeformableConv2d: B=4, C=256, O=256, H=W=64, K=3, pad=1, stride=1
// Round 5: K3 restructure (K1/K2 verbatim from round 4 = verified).
//   K3: tap-sized intervals (9 barriers, was 36), paired 8B corner loads
//       (boundary folded into shifted weight pairs, base col clamped to [0,62]),
//       16 waves = 8 producers + 8 consumers, 2x32KB double-buffered B-tile.
// Workspace: ws_off 1769472 B | ws_b 1179648 B | ws_a2 147456 B = 3096576 B.

typedef __attribute__((ext_vector_type(8))) short short8;
typedef __attribute__((ext_vector_type(8))) _Float16 half8;
typedef __attribute__((ext_vector_type(16))) float floatx16;

__device__ __forceinline__ unsigned bfbits(float f) {
    unsigned u;
    __builtin_memcpy(&u, &f, 4);
    return (u + 0x7fffu + ((u >> 16) & 1u)) >> 16;   // RNE f32->bf16
}
__device__ __forceinline__ unsigned pack_bf16(float lo, float hi) {
    return bfbits(lo) | (bfbits(hi) << 16);
}
__device__ __forceinline__ unsigned pack_f16(float lo, float hi) {
    _Float16 a = (_Float16)lo, b = (_Float16)hi;
    unsigned short ua, ub;
    __builtin_memcpy(&ua, &a, 2);
    __builtin_memcpy(&ub, &b, 2);
    return (unsigned)ua | ((unsigned)ub << 16);
}

// ---------------------------------------------------------------------------
// K1: weight pack (verbatim round 4).
// ---------------------------------------------------------------------------
__global__ __launch_bounds__(256) void weight_pack_kernel(
    const float* __restrict__ w, const float* __restrict__ off_w,
    const float* __restrict__ mask_w,
    unsigned short* __restrict__ ws_b, unsigned short* __restrict__ ws_a2)
{
    __shared__ float slab[32 * 289];
    const int bid = blockIdx.x;
    const int tid = threadIdx.x;

    if (bid < 64) {
        const int nt = bid >> 3, cb = bid & 7;
        const float* wbase = w + (size_t)nt * 32 * 2304 + cb * 288;
#pragma unroll
        for (int i = 0; i < 9; ++i) {
            int idx = i * 256 + tid;               // 0..2303
            int o = idx / 72, f4 = idx % 72;
            float4 v = *(const float4*)&wbase[(size_t)o * 2304 + f4 * 4];
            slab[o * 289 + f4 * 4 + 0] = v.x;
            slab[o * 289 + f4 * 4 + 1] = v.y;
            slab[o * 289 + f4 * 4 + 2] = v.z;
            slab[o * 289 + f4 * 4 + 3] = v.w;
        }
        __syncthreads();
#pragma unroll
        for (int pass = 0; pass < 5; ++pass) {
            int rid = pass * 8 + (tid >> 5);
            if (rid < 36) {
                int kk = rid >> 2, q = rid & 3;
                int no = tid & 31;
                unsigned pk[4];
#pragma unroll
                for (int i = 0; i < 4; ++i) {
                    float f0 = slab[no * 289 + (q * 8 + 2 * i) * 9 + kk];
                    float f1 = slab[no * 289 + (q * 8 + 2 * i + 1) * 9 + kk];
                    pk[i] = pack_bf16(f0, f1);
                }
                size_t u = ((size_t)nt * 288 + kk * 32 + cb * 4 + q) * 32 + no;
                *(uint4*)&ws_b[u * 8] = make_uint4(pk[0], pk[1], pk[2], pk[3]);
            }
        }
    } else {
        int e = (bid - 64) * 256 + tid;       // 0..9215
        int lan = e & 31;                     // oc row
        int ku = e >> 5;                      // 0..287
        int kk = ku >> 5;
        int c0 = (ku & 31) * 8;
        int o = lan;
        float f[8];
#pragma unroll
        for (int j = 0; j < 8; ++j) {
            int c = c0 + j;
            float v = 0.f;
            if (o < 18)      v = off_w[((size_t)o * 256 + c) * 9 + kk];
            else if (o < 27) v = mask_w[((size_t)(o - 18) * 256 + c) * 9 + kk];
            f[j] = v;
        }
        unsigned pk[4];
#pragma unroll
        for (int i = 0; i < 4; ++i) pk[i] = pack_f16(f[2 * i], f[2 * i + 1]);
        *(uint4*)&ws_a2[(size_t)e * 8] = make_uint4(pk[0], pk[1], pk[2], pk[3]);
    }
}

// ---------------------------------------------------------------------------
// K2: offset/mask conv via f16 MFMA (verbatim round 2/4, verified).
// ---------------------------------------------------------------------------
__global__ __launch_bounds__(512) void offmask_mfma_kernel(
    const float* __restrict__ x, const unsigned short* __restrict__ ws_a2,
    const float* __restrict__ off_b, const float* __restrict__ mask_b,
    float* __restrict__ ws_off)
{
    __shared__ uint4 bufB[2][2048];   // 64 KiB; aliased as red[] in epilogue
    const int bid = blockIdx.x;
    const int row = (bid & 7) * 32 + (bid >> 3);
    const int b = row >> 6, ho = row & 63;
    const int tid = threadIdx.x;
    const int l = tid & 63;
    const int w = tid >> 6;
    const int lan = l & 31, h = l >> 5;
    const float* xb = x + (size_t)b * 256 * 4096;

    floatx16 acc;
#pragma unroll
    for (int r = 0; r < 16; ++r) acc[r] = 0.f;

    const int n = l;                 // pixel within row
    const int ku0 = w;               // 0..7

    auto build = [&](int kk) {
        int ky = kk / 3, kx = kk - ky * 3;
        int hh = ho - 1 + ky;
        int px = n - 1 + kx;
        bool vh = (hh >= 0 && hh < 64);
        bool vx = (px >= 0 && px < 64);
        int base = hh * 64 + px;
        int buf = kk & 1;
#pragma unroll
        for (int j = 0; j < 4; ++j) {
            int ku = ku0 + 8 * j;
            int c0 = ku * 8;
            float v[8];
#pragma unroll
            for (int jj = 0; jj < 8; ++jj) {
                float t = 0.f;
                if (vh && vx) t = xb[(size_t)(c0 + jj) * 4096 + base];
                v[jj] = t;
            }
            unsigned pk[4];
#pragma unroll
            for (int i = 0; i < 4; ++i) pk[i] = pack_f16(v[2 * i], v[2 * i + 1]);
            bufB[buf][ku * 64 + n] = make_uint4(pk[0], pk[1], pk[2], pk[3]);
        }
    };

    const int ntile = w >> 2, kq = w & 3;
    auto domfma = [&](int kk) {
        int buf = kk & 1;
        const uint4* a4 = (const uint4*)ws_a2;
#pragma unroll
        for (int s4 = 0; s4 < 4; ++s4) {
            int s = kq * 4 + s4;         // K-step 0..15 within chunk
            int kul = s * 2 + h;         // local ku 0..31
            uint4 ua = a4[(size_t)(kk * 32 + kul) * 32 + lan];
            uint4 ub = bufB[buf][kul * 64 + ntile * 32 + lan];
            half8 a, bb;
            __builtin_memcpy(&a, &ua, 16);
            __builtin_memcpy(&bb, &ub, 16);
            acc = __builtin_amdgcn_mfma_f32_32x32x16_f16(a, bb, acc, 0, 0, 0);
        }
    };

    build(0);
    __syncthreads();
    for (int kk = 0; kk < 9; ++kk) {
        if (kk + 1 < 9) build(kk + 1);
        domfma(kk);
        __syncthreads();
    }

    // cross-wave partial-C reduction (4 K-quarters per n-tile)
    float* red = (float*)bufB;        // 8 waves x 64 lanes x 16 = 32 KiB
#pragma unroll
    for (int r = 0; r < 16; ++r) red[(w * 64 + l) * 16 + r] = acc[r];
    __syncthreads();
    for (int idx = tid; idx < 27 * 64; idx += 512) {
        int oc = idx >> 6, wo = idx & 63;
        int nt2 = wo >> 5, nn = wo & 31;
        int h2 = (oc >> 2) & 1;
        int r = (oc & 3) | ((oc >> 3) << 2);
        int lane2 = nn + 32 * h2;
        float s = 0.f;
#pragma unroll
        for (int kq2 = 0; kq2 < 4; ++kq2)
            s += red[((nt2 * 4 + kq2) * 64 + lane2) * 16 + r];
        float v;
        if (oc < 18) {
            v = s + off_b[oc];
        } else {
            float t = s + mask_b[oc - 18];
            v = 1.f / (1.f + expf(-t));
        }
        ws_off[(size_t)row * 1728 + idx] = v;
    }
}

// ---------------------------------------------------------------------------
// K3: fused deformable sampling + GEMM, tap-sized intervals.
// Block = one (b,ho) row; 16 waves: 8 producers (channels p*32..p*32+31,
// i.e. ku units p*4..p*4+3) + 8 consumers (m-tile cw, 2 n-tiles).
// Per interval (tap kk): producers gather with paired 8B corner loads and
// write a 256-K' B-tile; consumers run 16 K-steps (32 MFMAs) on prev tile.
// ---------------------------------------------------------------------------
__global__ __launch_bounds__(1024) void deform_gemm_kernel(
    const float* __restrict__ x, const float* __restrict__ ws_off,
    const unsigned short* __restrict__ ws_b, const float* __restrict__ bias,
    float* __restrict__ out)
{
    __shared__ float offs[1728];
    __shared__ float biasl[256];
    __shared__ uint4 tile[2][2048];   // [buf][ku(32)*64 + n] : 8 bf16 each, 2x32KB

    const int bid = blockIdx.x;
    const int row = (bid & 7) * 32 + (bid >> 3);
    const int b = row >> 6, ho = row & 63;
    const int tid = threadIdx.x;
    const int l = tid & 63;
    const int wid = tid >> 6;          // 0..15
    const int lan = l & 31, h = l >> 5;

    for (int i = tid; i < 1728; i += 1024) offs[i] = ws_off[(size_t)row * 1728 + i];
    if (tid < 256) biasl[tid] = bias[tid];
    __syncthreads();

    const int p = wid;          // producer unit (valid when wid < 8)
    const int cw = wid - 8;     // consumer m-tile (valid when wid >= 8)
    const float* xb = x + (size_t)b * 256 * 4096;
    const uint4* wb4 = (const uint4*)ws_b;

    // producer per-tap state: premultiplied weight pairs + row base offsets
    float a00 = 0.f, a01 = 0.f, a10 = 0.f, a11 = 0.f;
    int e0 = 0, e1 = 0;

    floatx16 acc0, acc1;
#pragma unroll
    for (int r = 0; r < 16; ++r) { acc0[r] = 0.f; acc1[r] = 0.f; }

    auto compute_tap = [&](int kk) {
        int ky = kk / 3, kx = kk - ky * 3;
        float dy = offs[(2 * kk) * 64 + l];
        float dx = offs[(2 * kk + 1) * 64 + l];
        float mk = offs[(18 + kk) * 64 + l];
        float py = (float)(ho - 1 + ky) + dy;
        float px = (float)(l - 1 + kx) + dx;
        float y0f = floorf(py), x0f = floorf(px);
        float wy1 = py - y0f, wx1 = px - x0f;
        float wy0 = 1.f - wy1, wx0 = 1.f - wx1;
        int y0 = (int)y0f, xi0 = (int)x0f;
        int y1 = y0 + 1;
        float vy0 = (y0 >= 0 && y0 < 64) ? 1.f : 0.f;
        float vy1 = (y1 >= 0 && y1 < 64) ? 1.f : 0.f;
        float vx0 = (xi0 >= 0 && xi0 < 64) ? 1.f : 0.f;
        float vx1 = (xi0 >= -1 && xi0 < 63) ? 1.f : 0.f;   // validity of xi0+1
        // paired-load weights: v.x at col bx, v.y at col bx+1, bx = clamp(xi0,0,62)
        float wxa, wxb;
        if (xi0 < 0)        { wxa = wx1 * vx1; wxb = 0.f; }        // corner1 lands at v.x
        else if (xi0 >= 63) { wxa = 0.f;       wxb = wx0 * vx0; }  // corner0 lands at v.y
        else                { wxa = wx0;       wxb = wx1; }        // both valid
        float wr0 = wy0 * vy0 * mk, wr1 = wy1 * vy1 * mk;
        a00 = wr0 * wxa; a01 = wr0 * wxb;
        a10 = wr1 * wxa; a11 = wr1 * wxb;
        int yc0 = min(max(y0, 0), 63), yc1 = min(max(y1, 0), 63);
        int bx = min(max(xi0, 0), 62);
        e0 = yc0 * 64 + bx;
        e1 = yc1 * 64 + bx;
    };

    auto sample_tap = [&](int buf) {
        const float* bp = xb + (size_t)(p * 32) * 4096;
#pragma unroll
        for (int u = 0; u < 4; ++u) {
            unsigned pk[4];
#pragma unroll
            for (int j = 0; j < 4; ++j) {
                const float* q0 = bp + (size_t)(u * 8 + 2 * j) * 4096;
                const float* q1 = q0 + 4096;
                float2 r0a, r0b, r1a, r1b;
                __builtin_memcpy(&r0a, q0 + e0, 8);
                __builtin_memcpy(&r0b, q0 + e1, 8);
                __builtin_memcpy(&r1a, q1 + e0, 8);
                __builtin_memcpy(&r1b, q1 + e1, 8);
                float v0 = a00 * r0a.x + a01 * r0a.y + a10 * r0b.x + a11 * r0b.y;
                float v1 = a00 * r1a.x + a01 * r1a.y + a10 * r1b.x + a11 * r1b.y;
                pk[j] = pack_bf16(v0, v1);
            }
            tile[buf][(p * 4 + u) * 64 + l] = make_uint4(pk[0], pk[1], pk[2], pk[3]);
        }
    };

    auto do_mfma = [&](int kk, int buf) {
#pragma unroll
        for (int ks = 0; ks < 16; ++ks) {
            int kul = ks * 2 + h;          // local ku 0..31
            uint4 ua = wb4[((size_t)cw * 288 + kk * 32 + kul) * 32 + lan];
            uint4 ub0 = tile[buf][kul * 64 + lan];
            uint4 ub1 = tile[buf][kul * 64 + 32 + lan];
            short8 a, b0, b1;
            __builtin_memcpy(&a, &ua, 16);
            __builtin_memcpy(&b0, &ub0, 16);
            __builtin_memcpy(&b1, &ub1, 16);
            acc0 = __builtin_amdgcn_mfma_f32_32x32x16_bf16(a, b0, acc0, 0, 0, 0);
            acc1 = __builtin_amdgcn_mfma_f32_32x32x16_bf16(a, b1, acc1, 0, 0, 0);
        }
    };

    if (wid < 8) { compute_tap(0); sample_tap(0); }
    __syncthreads();

    for (int kk = 0; kk < 9; ++kk) {
        if (wid < 8) {
            if (kk + 1 < 9) {
                compute_tap(kk + 1);
                sample_tap((kk + 1) & 1);
            }
        } else {
            do_mfma(kk, kk & 1);
        }
        __syncthreads();
    }

    if (wid >= 8) {
#pragma unroll
        for (int nt = 0; nt < 2; ++nt) {
#pragma unroll
            for (int r = 0; r < 16; ++r) {
                int o = cw * 32 + (r & 3) + 8 * (r >> 2) + 4 * h;
                int woo = nt * 32 + lan;
                float v = (nt == 0) ? acc0[r] : acc1[r];
                out[(((size_t)b * 256 + o) * 64 + ho) * 64 + woo] = v + biasl[o];
            }
        }
    }
}

extern "C" void kernel_launch(void* const* d_in, const int* in_sizes, int n_in,
                              void* d_out, int out_size, void* d_ws, size_t ws_size,
                              hipStream_t stream) {
    const float* x      = (const float*)d_in[0];
    const float* weight = (const float*)d_in[1];
    const float* bias   = (const float*)d_in[2];
    const float* off_w  = (const float*)d_in[3];
    const float* off_b  = (const float*)d_in[4];
    const float* mask_w = (const float*)d_in[5];
    const float* mask_b = (const float*)d_in[6];
    float* out = (float*)d_out;

    float* ws_off = (float*)d_ws;                                      // 1,769,472 B
    unsigned short* ws_b  = (unsigned short*)((char*)d_ws + 1769472);  // 1,179,648 B
    unsigned short* ws_a2 = (unsigned short*)((char*)d_ws + 2949120);  //   147,456 B

    hipLaunchKernelGGL(weight_pack_kernel, dim3(100), dim3(256), 0, stream,
                       weight, off_w, mask_w, ws_b, ws_a2);
    hipLaunchKernelGGL(offmask_mfma_kernel, dim3(256), dim3(512), 0, stream,
                       x, ws_a2, off_b, mask_b, ws_off);
    hipLaunchKernelGGL(deform_gemm_kernel, dim3(256), dim3(1024), 0, stream,
                       x, ws_off, ws_b, bias, out);
}